// Round 5
// baseline (523.361 us; speedup 1.0000x reference)
//
#include <hip/hip_runtime.h>
#include <stdint.h>

#define NNODES 8192
#define KP1 4096
#define KP2 2048
#define FIN 16
#define FH 32
#define COUT 2
#define STRA 320   // max off-diag nnz/row; mean ~163, sigma ~12.6 -> >12 sigma headroom
#define STRS 320

// Zero the shared edge counters (ws is poisoned 0xAA by the harness).
__global__ __launch_bounds__(256) void zero_cnt(int* __restrict__ c, int n)
{
    int i = blockIdx.x * 256 + threadIdx.x;
    if (i < n) c[i] = 0;
}

// Symmetric build: blocks [0,n) read only the UPPER triangle (incl. diagonal) of the
// 256MB adjacency (128MB total) and insert each edge (r,c), c>r, into BOTH row lists
// via global atomic slot allocation. Blocks [n, ...) compute Zf = Xf @ Wf (fout=32).
__global__ __launch_bounds__(256) void build_sym(const float* __restrict__ A, int n, int stride,
        int* __restrict__ ell, int* __restrict__ gcnt, int* __restrict__ diag,
        const float* __restrict__ Xf, const float* __restrict__ Wf, float* __restrict__ Zf, int kf)
{
    if ((int)blockIdx.x >= n) {
        int t = ((int)blockIdx.x - n) * 256 + threadIdx.x;
        int i = t >> 5;
        int f = t & 31;
        const float* xr = Xf + (size_t)i * kf;
        float acc = 0.0f;
        for (int k = 0; k < kf; ++k) acc += xr[k] * Wf[k * 32 + f];
        Zf[t] = acc;
        return;
    }
    __shared__ int dg;
    int row = blockIdx.x;
    if (threadIdx.x == 0) dg = 0;
    __syncthreads();
    const float4* arow4 = (const float4*)(A + (size_t)row * n);
    int n4 = n >> 2;
    int s4 = row >> 2;
    for (int c4 = s4 + threadIdx.x; c4 < n4; c4 += 256) {
        float4 v = arow4[c4];
        int cb = c4 << 2;
        if (v.x != 0.0f) {
            int c = cb;
            if (c == row) dg = 1;
            else if (c > row) {
                int p = atomicAdd(&gcnt[row], 1);
                if (p < stride) ell[(size_t)row * stride + p] = c;
                int q = atomicAdd(&gcnt[c], 1);
                if (q < stride) ell[(size_t)c * stride + q] = row;
            }
        }
        if (v.y != 0.0f) {
            int c = cb + 1;
            if (c == row) dg = 1;
            else if (c > row) {
                int p = atomicAdd(&gcnt[row], 1);
                if (p < stride) ell[(size_t)row * stride + p] = c;
                int q = atomicAdd(&gcnt[c], 1);
                if (q < stride) ell[(size_t)c * stride + q] = row;
            }
        }
        if (v.z != 0.0f) {
            int c = cb + 2;
            if (c == row) dg = 1;
            else if (c > row) {
                int p = atomicAdd(&gcnt[row], 1);
                if (p < stride) ell[(size_t)row * stride + p] = c;
                int q = atomicAdd(&gcnt[c], 1);
                if (q < stride) ell[(size_t)c * stride + q] = row;
            }
        }
        if (v.w != 0.0f) {
            int c = cb + 3;
            if (c == row) dg = 1;
            else if (c > row) {
                int p = atomicAdd(&gcnt[row], 1);
                if (p < stride) ell[(size_t)row * stride + p] = c;
                int q = atomicAdd(&gcnt[c], 1);
                if (q < stride) ell[(size_t)c * stride + q] = row;
            }
        }
    }
    __syncthreads();
    if (threadIdx.x == 0) diag[row] = dg;
}

// After ALL inserts: clamp counts and compute dnorm = rsqrt(deg_hat + 1e-10).
__global__ __launch_bounds__(256) void finalize_deg(const int* __restrict__ gcnt, const int* __restrict__ diag,
        int* __restrict__ rowcnt, float* __restrict__ dnorm, int n, int stride)
{
    int i = blockIdx.x * 256 + threadIdx.x;
    if (i >= n) return;
    int c = gcnt[i];
    rowcnt[i] = c < stride ? c : stride;
    dnorm[i] = rsqrtf((float)(c + diag[i] + 1) + 1e-10f);  // deg_hat = offdiag + a_ii + 1
}

// SpMM (F=32) + relu. One wave per row; 8 lanes per neighbor, float4 per lane.
// remap: neighbor id c -> row of Z. maskp: skip c if maskp[c]<0.
// If z4out != 0: instead of storing X/scores, fuse epilogue Z4r[row] = relu_row @ W4p (32x2).
__global__ __launch_bounds__(256) void spmm_f32(const int* __restrict__ ell, const int* __restrict__ rowcnt,
        const int* __restrict__ diag, const float* __restrict__ dnorm, const float* __restrict__ Z,
        const int* __restrict__ remap, const int* __restrict__ maskp,
        float* __restrict__ X, float* __restrict__ scores, const float* __restrict__ svec,
        const float* __restrict__ W4p, float* __restrict__ z4out,
        int n, int stride)
{
    int wid = (blockIdx.x * 256 + threadIdx.x) >> 6;
    int lane = threadIdx.x & 63;
    if (wid >= n) return;
    int g = lane >> 3;   // neighbor sub-slot 0..7
    int q = lane & 7;    // feature quad 0..7
    int cnt = rowcnt[wid];
    const int* erow = ell + (size_t)wid * stride;
    float ax = 0.0f, ay = 0.0f, az = 0.0f, aw = 0.0f;
    for (int it = g; it < cnt; it += 8) {
        int c = erow[it];
        if (maskp && maskp[c] < 0) continue;
        int zc = c;
        if (remap) zc = remap[c];
        float dn = dnorm[c];
        const float4* zp = (const float4*)(Z + (size_t)zc * 32);
        float4 zv = zp[q];
        ax += dn * zv.x;
        ay += dn * zv.y;
        az += dn * zv.z;
        aw += dn * zv.w;
    }
    ax += __shfl_xor(ax, 8);
    ay += __shfl_xor(ay, 8);
    az += __shfl_xor(az, 8);
    aw += __shfl_xor(aw, 8);
    ax += __shfl_xor(ax, 16);
    ay += __shfl_xor(ay, 16);
    az += __shfl_xor(az, 16);
    aw += __shfl_xor(aw, 16);
    ax += __shfl_xor(ax, 32);
    ay += __shfl_xor(ay, 32);
    az += __shfl_xor(az, 32);
    aw += __shfl_xor(aw, 32);
    if (g == 0) {   // lanes 0..7 hold the full sum for feature quad q
        float dr = dnorm[wid];
        int selfok = 1;
        if (maskp && maskp[wid] < 0) selfok = 0;
        if (selfok) {
            int zc = wid;
            if (remap) zc = remap[wid];
            const float4* zp = (const float4*)(Z + (size_t)zc * 32);
            float4 zv = zp[q];
            float cf = (float)(diag[wid] + 1) * dr;
            ax += cf * zv.x;
            ay += cf * zv.y;
            az += cf * zv.z;
            aw += cf * zv.w;
        }
        float ox = fmaxf(dr * ax, 0.0f);
        float oy = fmaxf(dr * ay, 0.0f);
        float oz = fmaxf(dr * az, 0.0f);
        float ow = fmaxf(dr * aw, 0.0f);
        if (z4out) {
            // fused (32x2) GEMM: row @ W4 -> 2 outputs; reduce partials over the 8 q-lanes
            int kb = q * 4;
            float p0 = ox * W4p[(kb + 0) * 2 + 0] + oy * W4p[(kb + 1) * 2 + 0]
                     + oz * W4p[(kb + 2) * 2 + 0] + ow * W4p[(kb + 3) * 2 + 0];
            float p1 = ox * W4p[(kb + 0) * 2 + 1] + oy * W4p[(kb + 1) * 2 + 1]
                     + oz * W4p[(kb + 2) * 2 + 1] + ow * W4p[(kb + 3) * 2 + 1];
            p0 += __shfl_xor(p0, 1);
            p1 += __shfl_xor(p1, 1);
            p0 += __shfl_xor(p0, 2);
            p1 += __shfl_xor(p1, 2);
            p0 += __shfl_xor(p0, 4);
            p1 += __shfl_xor(p1, 4);
            if (q == 0) {
                float2 r;
                r.x = p0;
                r.y = p1;
                ((float2*)z4out)[wid] = r;
            }
        } else {
            float4 o;
            o.x = ox; o.y = oy; o.z = oz; o.w = ow;
            float4* xp = (float4*)(X + (size_t)wid * 32);
            xp[q] = o;
            if (scores) {
                const float4* sp = (const float4*)svec;
                float4 sv = sp[q];
                float p = o.x * sv.x + o.y * sv.y + o.z * sv.z + o.w * sv.w;
                p += __shfl_xor(p, 1);
                p += __shfl_xor(p, 2);
                p += __shfl_xor(p, 4);
                if (q == 0) scores[wid] = p;
            }
        }
    }
}

// Final SpMM (F=2) + 2-way softmax. Zr is rank-space (K1 x 2); node c contributes
// Zr[gat[c]] if gat[c]>=0 else 0 (unpool1 folded into the gather).
__global__ __launch_bounds__(256) void spmm_out(const int* __restrict__ ell, const int* __restrict__ rowcnt,
        const int* __restrict__ diag, const float* __restrict__ dnorm, const float* __restrict__ Zr,
        const int* __restrict__ gat, float* __restrict__ out, int n, int stride)
{
    int wid = (blockIdx.x * 256 + threadIdx.x) >> 6;
    int lane = threadIdx.x & 63;
    if (wid >= n) return;
    int cnt = rowcnt[wid];
    const int* erow = ell + (size_t)wid * stride;
    const float2* Z2 = (const float2*)Zr;
    float ax = 0.0f, ay = 0.0f;
    for (int it = lane; it < cnt; it += 64) {
        int c = erow[it];
        int rk = gat[c];
        if (rk >= 0) {
            float dn = dnorm[c];
            float2 zv = Z2[rk];
            ax += dn * zv.x;
            ay += dn * zv.y;
        }
    }
    ax += __shfl_xor(ax, 1);
    ay += __shfl_xor(ay, 1);
    ax += __shfl_xor(ax, 2);
    ay += __shfl_xor(ay, 2);
    ax += __shfl_xor(ax, 4);
    ay += __shfl_xor(ay, 4);
    ax += __shfl_xor(ax, 8);
    ay += __shfl_xor(ay, 8);
    ax += __shfl_xor(ax, 16);
    ay += __shfl_xor(ay, 16);
    ax += __shfl_xor(ax, 32);
    ay += __shfl_xor(ay, 32);
    if (lane == 0) {
        float dr = dnorm[wid];
        int rks = gat[wid];
        if (rks >= 0) {
            float cf = (float)(diag[wid] + 1) * dr;
            float2 zs = Z2[rks];
            ax += cf * zs.x;
            ay += cf * zs.y;
        }
        float v0 = dr * ax;
        float v1 = dr * ay;
        float m = fmaxf(v0, v1);
        float e0 = __expf(v0 - m);
        float e1 = __expf(v1 - m);
        float inv = 1.0f / (e0 + e1);
        float2 r;
        r.x = e0 * inv;
        r.y = e1 * inv;
        ((float2*)out)[wid] = r;
    }
}

// Exact top-K (jax.lax.top_k set semantics: value desc, index-asc ties), block 0 only.
// Blocks >= 1 compute Zf = Xf @ Wf (fout=32) — independent co-launched work.
__global__ __launch_bounds__(256) void topk_feat(const float* __restrict__ scores, int n, int K,
        int* __restrict__ rank, int* __restrict__ idxlist,
        const float* __restrict__ Xf, const float* __restrict__ Wf, float* __restrict__ Zf, int kf)
{
    if (blockIdx.x != 0) {
        int t = ((int)blockIdx.x - 1) * 256 + threadIdx.x;
        int i = t >> 5;
        int f = t & 31;
        const float* xr = Xf + (size_t)i * kf;
        float acc = 0.0f;
        for (int k = 0; k < kf; ++k) acc += xr[k] * Wf[k * 32 + f];
        Zf[t] = acc;
        return;
    }
    __shared__ unsigned int km_s[8192];
    __shared__ unsigned int part_s[256];
    __shared__ unsigned int histp[4][256];
    __shared__ unsigned int sh_pref;
    __shared__ unsigned int sh_rem;
    int tid = threadIdx.x;
    int wv = tid >> 6;
    int per = n >> 8;       // 32 (N=8192) or 16 (N=4096)
    int base = tid * per;
    for (int e = 0; e < per; ++e) {
        int v = base + e;
        unsigned int u = __float_as_uint(scores[v]);
        unsigned int m;
        if (u & 0x80000000u) m = ~u; else m = u | 0x80000000u;  // monotone asc in float
        km_s[v] = ~m;                                           // asc in km == desc in score
    }
    if (tid == 0) { sh_pref = 0u; sh_rem = (unsigned int)K; }
    __syncthreads();
    for (int bp = 3; bp >= 0; --bp) {
        histp[0][tid] = 0u;
        histp[1][tid] = 0u;
        histp[2][tid] = 0u;
        histp[3][tid] = 0u;
        __syncthreads();
        unsigned int maskhi = 0u;
        if (bp < 3) maskhi = 0xFFFFFFFFu << ((bp + 1) * 8);
        unsigned int pref = sh_pref;
        unsigned int rem = sh_rem;
        for (int e = 0; e < per; ++e) {
            unsigned int km = km_s[base + e];
            if ((km & maskhi) == pref) atomicAdd(&histp[wv][(km >> (bp * 8)) & 255u], 1u);
        }
        __syncthreads();
        // thread tid owns bin tid; inclusive scan of totals across 256 bins
        unsigned int tot = histp[0][tid] + histp[1][tid] + histp[2][tid] + histp[3][tid];
        part_s[tid] = tot;
        __syncthreads();
        for (int offd = 1; offd < 256; offd <<= 1) {
            unsigned int add = 0u;
            if (tid >= offd) add = part_s[tid - offd];
            __syncthreads();
            part_s[tid] += add;
            __syncthreads();
        }
        unsigned int cum = part_s[tid];
        if (tot != 0u && cum >= rem && cum - tot < rem) {  // unique boundary bin
            sh_pref = pref | ((unsigned int)tid << (bp * 8));
            sh_rem = rem - (cum - tot);
        }
        __syncthreads();
    }
    unsigned int T = sh_pref;       // K-th smallest km
    unsigned int need_eq = sh_rem;  // how many km==T to take (lowest node index first)
    // packed counts: high16 = #(km<T), low16 = #(km==T)
    unsigned int run = 0u;
    for (int e = 0; e < per; ++e) {
        unsigned int km = km_s[base + e];
        if (km < T) run += 0x10000u;
        else if (km == T) run += 1u;
    }
    part_s[tid] = run;
    __syncthreads();
    for (int offd = 1; offd < 256; offd <<= 1) {
        unsigned int add = 0u;
        if (tid >= offd) add = part_s[tid - offd];
        __syncthreads();
        part_s[tid] += add;
        __syncthreads();
    }
    unsigned int cur = part_s[tid] - run;   // exclusive prefix for this thread's chunk
    for (int e = 0; e < per; ++e) {
        int v = base + e;
        unsigned int km = km_s[v];
        unsigned int ltb = cur >> 16;
        unsigned int eqb = cur & 0xFFFFu;
        unsigned int eqs = eqb < need_eq ? eqb : need_eq;  // selected equals before v
        int sel = 0;
        if (km < T) { sel = 1; cur += 0x10000u; }
        else if (km == T) { if (eqb < need_eq) sel = 1; cur += 1u; }
        if (sel) {
            int r = (int)(ltb + eqs);       // rank = #selected with index < v
            rank[v] = r;
            idxlist[r] = v;
        } else {
            rank[v] = -1;
        }
    }
}

// Build subgraph ELL for A1p = a[idx1][:,idx1] by filtering the main ELL
// through rank1 (wave-compaction via ballot). One wave per subgraph row.
__global__ __launch_bounds__(256) void build_subell(const int* __restrict__ ellA, const int* __restrict__ rowcntA,
        const int* __restrict__ diagA, const int* __restrict__ idx1, const int* __restrict__ rank1,
        int* __restrict__ ellS, int* __restrict__ rowcntS, int* __restrict__ diagS, float* __restrict__ dnormS,
        int k1, int strideA, int strideS)
{
    int wid = (blockIdx.x * 256 + threadIdx.x) >> 6;
    int lane = threadIdx.x & 63;
    if (wid >= k1) return;
    int r = idx1[wid];
    int cnt = rowcntA[r];
    const int* erow = ellA + (size_t)r * strideA;
    int* srow = ellS + (size_t)wid * strideS;
    int outn = 0;
    for (int t0 = 0; t0 < cnt; t0 += 64) {
        int it = t0 + lane;
        int rk = -1;
        if (it < cnt) rk = rank1[erow[it]];
        unsigned long long b = __ballot(rk >= 0);
        int ofs = __popcll(b & ((1ull << lane) - 1ull));
        if (rk >= 0) srow[outn + ofs] = rk;
        outn += __popcll(b);
    }
    if (lane == 0) {
        int dg = diagA[r];              // A1p diagonal entry = a[r][r]
        rowcntS[wid] = outn;
        diagS[wid] = dg;
        dnormS[wid] = rsqrtf((float)(outn + dg + 1) + 1e-10f);
    }
}

#define CARVE(type, name, bytes) \
    type name = (type)wp; wp += (((size_t)(bytes)) + 255) & ~((size_t)255);

extern "C" void kernel_launch(void* const* d_in, const int* in_sizes, int n_in,
                              void* d_out, int out_size, void* d_ws, size_t ws_size,
                              hipStream_t stream)
{
    const float* x  = (const float*)d_in[0];
    const float* a  = (const float*)d_in[1];
    const float* W1 = (const float*)d_in[2];
    const float* W2 = (const float*)d_in[3];
    const float* W3 = (const float*)d_in[4];
    const float* W4 = (const float*)d_in[5];
    const float* s1 = (const float*)d_in[6];
    const float* s2 = (const float*)d_in[7];
    float* out = (float*)d_out;
    (void)in_sizes; (void)n_in; (void)out_size; (void)ws_size;

    char* wp = (char*)d_ws;
    CARVE(int*,   ellA,  (size_t)NNODES * STRA * sizeof(int));   // 10.5 MB
    CARVE(int*,   gcntA, NNODES * sizeof(int));
    CARVE(int*,   cntA,  NNODES * sizeof(int));
    CARVE(int*,   diagA, NNODES * sizeof(int));
    CARVE(float*, dnA,   NNODES * sizeof(float));
    CARVE(float*, Z1,    (size_t)NNODES * FH * sizeof(float));
    CARVE(float*, X1,    (size_t)NNODES * FH * sizeof(float));
    CARVE(float*, sc1,   NNODES * sizeof(float));
    CARVE(int*,   rank1, NNODES * sizeof(int));
    CARVE(int*,   idx1,  NNODES * sizeof(int));
    CARVE(int*,   ellS,  (size_t)KP1 * STRS * sizeof(int));      // 5.2 MB
    CARVE(int*,   cntS,  KP1 * sizeof(int));
    CARVE(int*,   diagS, KP1 * sizeof(int));
    CARVE(float*, dnS,   KP1 * sizeof(float));
    CARVE(float*, Z2f,   (size_t)NNODES * FH * sizeof(float));   // X1@W2 over ALL rows
    CARVE(float*, X2,    (size_t)KP1 * FH * sizeof(float));
    CARVE(float*, sc2,   KP1 * sizeof(float));
    CARVE(int*,   rank2, KP1 * sizeof(int));
    CARVE(int*,   idx2,  KP1 * sizeof(int));
    CARVE(float*, Z3f,   (size_t)KP1 * FH * sizeof(float));      // X2@W3 over all pooled rows
    CARVE(float*, Z4r,   (size_t)KP1 * COUT * sizeof(float));    // rank-space X3@W4

    // 1) zero edge counters (ws is poisoned)
    zero_cnt<<<NNODES / 256, 256, 0, stream>>>(gcntA, NNODES);
    // 2) symmetric half-read build (128MB) + co-launched Z1 = x@W1
    build_sym<<<NNODES + (NNODES * FH) / 256, 256, 0, stream>>>(
        a, NNODES, STRA, ellA, gcntA, diagA, x, W1, Z1, FIN);
    // 3) finalize degrees
    finalize_deg<<<NNODES / 256, 256, 0, stream>>>(gcntA, diagA, cntA, dnA, NNODES, STRA);
    // 4) GCN1: X1 = relu(Anorm@Z1), sc1 = X1@s1
    spmm_f32<<<NNODES / 4, 256, 0, stream>>>(ellA, cntA, diagA, dnA, Z1,
        (const int*)0, (const int*)0, X1, sc1, s1, (const float*)0, (float*)0, NNODES, STRA);
    // 5) pool1 top-k (block 0) + Z2f = X1@W2 over ALL rows (blocks 1..)
    topk_feat<<<1 + (NNODES * FH) / 256, 256, 0, stream>>>(
        sc1, NNODES, KP1, rank1, idx1, X1, W2, Z2f, FH);
    // 6) subgraph ELL
    build_subell<<<KP1 / 4, 256, 0, stream>>>(ellA, cntA, diagA, idx1, rank1,
        ellS, cntS, diagS, dnS, KP1, STRA, STRS);
    // 7) GCN2 on subgraph (Z gathered from full space via idx1): X2, sc2
    spmm_f32<<<KP1 / 4, 256, 0, stream>>>(ellS, cntS, diagS, dnS, Z2f,
        idx1, (const int*)0, X2, sc2, s2, (const float*)0, (float*)0, KP1, STRS);
    // 8) pool2 top-k (block 0) + Z3f = X2@W3 over all pooled rows (blocks 1..)
    topk_feat<<<1 + (KP1 * FH) / 256, 256, 0, stream>>>(
        sc2, KP1, KP2, rank2, idx2, X2, W3, Z3f, FH);
    // 9) GCN3 with pool2 mask + fused W4 epilogue -> Z4r = relu(Anorm_S@Z3_masked)@W4
    spmm_f32<<<KP1 / 4, 256, 0, stream>>>(ellS, cntS, diagS, dnS, Z3f,
        (const int*)0, rank2, (float*)0, (float*)0, (const float*)0, W4, Z4r, KP1, STRS);
    // 10) GCN4 + softmax (unpool1 folded into rank1 gather)
    spmm_out<<<NNODES / 4, 256, 0, stream>>>(ellA, cntA, diagA, dnA, Z4r, rank1, out, NNODES, STRA);
}

// Round 6
// 477.552 us; speedup vs baseline: 1.0959x; 1.0959x over previous
//
#include <hip/hip_runtime.h>
#include <stdint.h>

#define NNODES 8192
#define KP1 4096
#define KP2 2048
#define FIN 16
#define FH 32
#define COUT 2
#define STRA 320   // max off-diag nnz/row; mean ~163, sigma ~12.6 -> >12 sigma headroom
#define STRS 320

// Pass 1 (fused): blocks [0,n) stream the 256MB dense adjacency ONCE (float4, coalesced,
// block-local LDS counting) -> ELL; blocks [n,...) compute Zf = Xf @ Wf (fout=32).
__global__ __launch_bounds__(256) void build_ell(const float* __restrict__ A, int n, int stride,
        int* __restrict__ ell, int* __restrict__ rowcnt, int* __restrict__ diag, float* __restrict__ dnorm,
        const float* __restrict__ Xf, const float* __restrict__ Wf, float* __restrict__ Zf, int kf)
{
    if ((int)blockIdx.x >= n) {
        int t = ((int)blockIdx.x - n) * 256 + threadIdx.x;
        int i = t >> 5;
        int f = t & 31;
        const float* xr = Xf + (size_t)i * kf;
        float acc = 0.0f;
        for (int k = 0; k < kf; ++k) acc += xr[k] * Wf[k * 32 + f];
        Zf[t] = acc;
        return;
    }
    __shared__ int cnt;
    __shared__ int dg;
    int row = blockIdx.x;
    if (threadIdx.x == 0) { cnt = 0; dg = 0; }
    __syncthreads();
    const float4* arow4 = (const float4*)(A + (size_t)row * n);
    int* erow = ell + (size_t)row * stride;
    int n4 = n >> 2;
    for (int c4 = threadIdx.x; c4 < n4; c4 += 256) {
        float4 v = arow4[c4];
        int cb = c4 << 2;
        if (v.x != 0.0f) {
            if (cb == row) dg = 1;
            else { int p = atomicAdd(&cnt, 1); if (p < stride) erow[p] = cb; }
        }
        if (v.y != 0.0f) {
            int c = cb + 1;
            if (c == row) dg = 1;
            else { int p = atomicAdd(&cnt, 1); if (p < stride) erow[p] = c; }
        }
        if (v.z != 0.0f) {
            int c = cb + 2;
            if (c == row) dg = 1;
            else { int p = atomicAdd(&cnt, 1); if (p < stride) erow[p] = c; }
        }
        if (v.w != 0.0f) {
            int c = cb + 3;
            if (c == row) dg = 1;
            else { int p = atomicAdd(&cnt, 1); if (p < stride) erow[p] = c; }
        }
    }
    __syncthreads();
    if (threadIdx.x == 0) {
        int cf = cnt;
        rowcnt[row] = cf < stride ? cf : stride;
        diag[row] = dg;
        // deg_hat = offdiag_count + a_ii + 1 (self loop); all values are exactly 1.0
        dnorm[row] = rsqrtf((float)(cf + dg + 1) + 1e-10f);
    }
}

// SpMM (F=32) + relu. One wave per row; 8 lanes per neighbor, float4 per lane.
// remap: neighbor id c -> row of Z. maskp: skip c if maskp[c]<0.
// If z4out != 0: instead of storing X/scores, fuse epilogue Z4r[row] = relu_row @ W4p (32x2).
__global__ __launch_bounds__(256) void spmm_f32(const int* __restrict__ ell, const int* __restrict__ rowcnt,
        const int* __restrict__ diag, const float* __restrict__ dnorm, const float* __restrict__ Z,
        const int* __restrict__ remap, const int* __restrict__ maskp,
        float* __restrict__ X, float* __restrict__ scores, const float* __restrict__ svec,
        const float* __restrict__ W4p, float* __restrict__ z4out,
        int n, int stride)
{
    int wid = (blockIdx.x * 256 + threadIdx.x) >> 6;
    int lane = threadIdx.x & 63;
    if (wid >= n) return;
    int g = lane >> 3;   // neighbor sub-slot 0..7
    int q = lane & 7;    // feature quad 0..7
    int cnt = rowcnt[wid];
    const int* erow = ell + (size_t)wid * stride;
    float ax = 0.0f, ay = 0.0f, az = 0.0f, aw = 0.0f;
    for (int it = g; it < cnt; it += 8) {
        int c = erow[it];
        if (maskp && maskp[c] < 0) continue;
        int zc = c;
        if (remap) zc = remap[c];
        float dn = dnorm[c];
        const float4* zp = (const float4*)(Z + (size_t)zc * 32);
        float4 zv = zp[q];
        ax += dn * zv.x;
        ay += dn * zv.y;
        az += dn * zv.z;
        aw += dn * zv.w;
    }
    ax += __shfl_xor(ax, 8);
    ay += __shfl_xor(ay, 8);
    az += __shfl_xor(az, 8);
    aw += __shfl_xor(aw, 8);
    ax += __shfl_xor(ax, 16);
    ay += __shfl_xor(ay, 16);
    az += __shfl_xor(az, 16);
    aw += __shfl_xor(aw, 16);
    ax += __shfl_xor(ax, 32);
    ay += __shfl_xor(ay, 32);
    az += __shfl_xor(az, 32);
    aw += __shfl_xor(aw, 32);
    if (g == 0) {   // lanes 0..7 hold the full sum for feature quad q
        float dr = dnorm[wid];
        int selfok = 1;
        if (maskp && maskp[wid] < 0) selfok = 0;
        if (selfok) {
            int zc = wid;
            if (remap) zc = remap[wid];
            const float4* zp = (const float4*)(Z + (size_t)zc * 32);
            float4 zv = zp[q];
            float cf = (float)(diag[wid] + 1) * dr;
            ax += cf * zv.x;
            ay += cf * zv.y;
            az += cf * zv.z;
            aw += cf * zv.w;
        }
        float ox = fmaxf(dr * ax, 0.0f);
        float oy = fmaxf(dr * ay, 0.0f);
        float oz = fmaxf(dr * az, 0.0f);
        float ow = fmaxf(dr * aw, 0.0f);
        if (z4out) {
            // fused (32x2) GEMM: row @ W4 -> 2 outputs; reduce partials over the 8 q-lanes
            int kb = q * 4;
            float p0 = ox * W4p[(kb + 0) * 2 + 0] + oy * W4p[(kb + 1) * 2 + 0]
                     + oz * W4p[(kb + 2) * 2 + 0] + ow * W4p[(kb + 3) * 2 + 0];
            float p1 = ox * W4p[(kb + 0) * 2 + 1] + oy * W4p[(kb + 1) * 2 + 1]
                     + oz * W4p[(kb + 2) * 2 + 1] + ow * W4p[(kb + 3) * 2 + 1];
            p0 += __shfl_xor(p0, 1);
            p1 += __shfl_xor(p1, 1);
            p0 += __shfl_xor(p0, 2);
            p1 += __shfl_xor(p1, 2);
            p0 += __shfl_xor(p0, 4);
            p1 += __shfl_xor(p1, 4);
            if (q == 0) {
                float2 r;
                r.x = p0;
                r.y = p1;
                ((float2*)z4out)[wid] = r;
            }
        } else {
            float4 o;
            o.x = ox; o.y = oy; o.z = oz; o.w = ow;
            float4* xp = (float4*)(X + (size_t)wid * 32);
            xp[q] = o;
            if (scores) {
                const float4* sp = (const float4*)svec;
                float4 sv = sp[q];
                float p = o.x * sv.x + o.y * sv.y + o.z * sv.z + o.w * sv.w;
                p += __shfl_xor(p, 1);
                p += __shfl_xor(p, 2);
                p += __shfl_xor(p, 4);
                if (q == 0) scores[wid] = p;
            }
        }
    }
}

// Final SpMM (F=2) + 2-way softmax. Zr is rank-space (K1 x 2); node c contributes
// Zr[gat[c]] if gat[c]>=0 else 0 (unpool1 folded into the gather).
__global__ __launch_bounds__(256) void spmm_out(const int* __restrict__ ell, const int* __restrict__ rowcnt,
        const int* __restrict__ diag, const float* __restrict__ dnorm, const float* __restrict__ Zr,
        const int* __restrict__ gat, float* __restrict__ out, int n, int stride)
{
    int wid = (blockIdx.x * 256 + threadIdx.x) >> 6;
    int lane = threadIdx.x & 63;
    if (wid >= n) return;
    int cnt = rowcnt[wid];
    const int* erow = ell + (size_t)wid * stride;
    const float2* Z2 = (const float2*)Zr;
    float ax = 0.0f, ay = 0.0f;
    for (int it = lane; it < cnt; it += 64) {
        int c = erow[it];
        int rk = gat[c];
        if (rk >= 0) {
            float dn = dnorm[c];
            float2 zv = Z2[rk];
            ax += dn * zv.x;
            ay += dn * zv.y;
        }
    }
    ax += __shfl_xor(ax, 1);
    ay += __shfl_xor(ay, 1);
    ax += __shfl_xor(ax, 2);
    ay += __shfl_xor(ay, 2);
    ax += __shfl_xor(ax, 4);
    ay += __shfl_xor(ay, 4);
    ax += __shfl_xor(ax, 8);
    ay += __shfl_xor(ay, 8);
    ax += __shfl_xor(ax, 16);
    ay += __shfl_xor(ay, 16);
    ax += __shfl_xor(ax, 32);
    ay += __shfl_xor(ay, 32);
    if (lane == 0) {
        float dr = dnorm[wid];
        int rks = gat[wid];
        if (rks >= 0) {
            float cf = (float)(diag[wid] + 1) * dr;
            float2 zs = Z2[rks];
            ax += cf * zs.x;
            ay += cf * zs.y;
        }
        float v0 = dr * ax;
        float v1 = dr * ay;
        float m = fmaxf(v0, v1);
        float e0 = __expf(v0 - m);
        float e1 = __expf(v1 - m);
        float inv = 1.0f / (e0 + e1);
        float2 r;
        r.x = e0 * inv;
        r.y = e1 * inv;
        ((float2*)out)[wid] = r;
    }
}

// Exact top-K (jax.lax.top_k set semantics: value desc, index-asc ties), block 0 only.
// Blocks >= 1 compute Zf = Xf @ Wf (fout=32) — independent co-launched work.
__global__ __launch_bounds__(256) void topk_feat(const float* __restrict__ scores, int n, int K,
        int* __restrict__ rank, int* __restrict__ idxlist,
        const float* __restrict__ Xf, const float* __restrict__ Wf, float* __restrict__ Zf, int kf)
{
    if (blockIdx.x != 0) {
        int t = ((int)blockIdx.x - 1) * 256 + threadIdx.x;
        int i = t >> 5;
        int f = t & 31;
        const float* xr = Xf + (size_t)i * kf;
        float acc = 0.0f;
        for (int k = 0; k < kf; ++k) acc += xr[k] * Wf[k * 32 + f];
        Zf[t] = acc;
        return;
    }
    __shared__ unsigned int km_s[8192];
    __shared__ unsigned int part_s[256];
    __shared__ unsigned int histp[4][256];
    __shared__ unsigned int sh_pref;
    __shared__ unsigned int sh_rem;
    int tid = threadIdx.x;
    int wv = tid >> 6;
    int per = n >> 8;       // 32 (N=8192) or 16 (N=4096)
    int base = tid * per;
    for (int e = 0; e < per; ++e) {
        int v = base + e;
        unsigned int u = __float_as_uint(scores[v]);
        unsigned int m;
        if (u & 0x80000000u) m = ~u; else m = u | 0x80000000u;  // monotone asc in float
        km_s[v] = ~m;                                           // asc in km == desc in score
    }
    if (tid == 0) { sh_pref = 0u; sh_rem = (unsigned int)K; }
    __syncthreads();
    for (int bp = 3; bp >= 0; --bp) {
        histp[0][tid] = 0u;
        histp[1][tid] = 0u;
        histp[2][tid] = 0u;
        histp[3][tid] = 0u;
        __syncthreads();
        unsigned int maskhi = 0u;
        if (bp < 3) maskhi = 0xFFFFFFFFu << ((bp + 1) * 8);
        unsigned int pref = sh_pref;
        unsigned int rem = sh_rem;
        for (int e = 0; e < per; ++e) {
            unsigned int km = km_s[base + e];
            if ((km & maskhi) == pref) atomicAdd(&histp[wv][(km >> (bp * 8)) & 255u], 1u);
        }
        __syncthreads();
        // thread tid owns bin tid; inclusive scan of totals across 256 bins
        unsigned int tot = histp[0][tid] + histp[1][tid] + histp[2][tid] + histp[3][tid];
        part_s[tid] = tot;
        __syncthreads();
        for (int offd = 1; offd < 256; offd <<= 1) {
            unsigned int add = 0u;
            if (tid >= offd) add = part_s[tid - offd];
            __syncthreads();
            part_s[tid] += add;
            __syncthreads();
        }
        unsigned int cum = part_s[tid];
        if (tot != 0u && cum >= rem && cum - tot < rem) {  // unique boundary bin
            sh_pref = pref | ((unsigned int)tid << (bp * 8));
            sh_rem = rem - (cum - tot);
        }
        __syncthreads();
    }
    unsigned int T = sh_pref;       // K-th smallest km
    unsigned int need_eq = sh_rem;  // how many km==T to take (lowest node index first)
    // packed counts: high16 = #(km<T), low16 = #(km==T)
    unsigned int run = 0u;
    for (int e = 0; e < per; ++e) {
        unsigned int km = km_s[base + e];
        if (km < T) run += 0x10000u;
        else if (km == T) run += 1u;
    }
    part_s[tid] = run;
    __syncthreads();
    for (int offd = 1; offd < 256; offd <<= 1) {
        unsigned int add = 0u;
        if (tid >= offd) add = part_s[tid - offd];
        __syncthreads();
        part_s[tid] += add;
        __syncthreads();
    }
    unsigned int cur = part_s[tid] - run;   // exclusive prefix for this thread's chunk
    for (int e = 0; e < per; ++e) {
        int v = base + e;
        unsigned int km = km_s[v];
        unsigned int ltb = cur >> 16;
        unsigned int eqb = cur & 0xFFFFu;
        unsigned int eqs = eqb < need_eq ? eqb : need_eq;  // selected equals before v
        int sel = 0;
        if (km < T) { sel = 1; cur += 0x10000u; }
        else if (km == T) { if (eqb < need_eq) sel = 1; cur += 1u; }
        if (sel) {
            int r = (int)(ltb + eqs);       // rank = #selected with index < v
            rank[v] = r;
            idxlist[r] = v;
        } else {
            rank[v] = -1;
        }
    }
}

// Build subgraph ELL for A1p = a[idx1][:,idx1] by filtering the main ELL
// through rank1 (wave-compaction via ballot). One wave per subgraph row.
__global__ __launch_bounds__(256) void build_subell(const int* __restrict__ ellA, const int* __restrict__ rowcntA,
        const int* __restrict__ diagA, const int* __restrict__ idx1, const int* __restrict__ rank1,
        int* __restrict__ ellS, int* __restrict__ rowcntS, int* __restrict__ diagS, float* __restrict__ dnormS,
        int k1, int strideA, int strideS)
{
    int wid = (blockIdx.x * 256 + threadIdx.x) >> 6;
    int lane = threadIdx.x & 63;
    if (wid >= k1) return;
    int r = idx1[wid];
    int cnt = rowcntA[r];
    const int* erow = ellA + (size_t)r * strideA;
    int* srow = ellS + (size_t)wid * strideS;
    int outn = 0;
    for (int t0 = 0; t0 < cnt; t0 += 64) {
        int it = t0 + lane;
        int rk = -1;
        if (it < cnt) rk = rank1[erow[it]];
        unsigned long long b = __ballot(rk >= 0);
        int ofs = __popcll(b & ((1ull << lane) - 1ull));
        if (rk >= 0) srow[outn + ofs] = rk;
        outn += __popcll(b);
    }
    if (lane == 0) {
        int dg = diagA[r];              // A1p diagonal entry = a[r][r]
        rowcntS[wid] = outn;
        diagS[wid] = dg;
        dnormS[wid] = rsqrtf((float)(outn + dg + 1) + 1e-10f);
    }
}

#define CARVE(type, name, bytes) \
    type name = (type)wp; wp += (((size_t)(bytes)) + 255) & ~((size_t)255);

extern "C" void kernel_launch(void* const* d_in, const int* in_sizes, int n_in,
                              void* d_out, int out_size, void* d_ws, size_t ws_size,
                              hipStream_t stream)
{
    const float* x  = (const float*)d_in[0];
    const float* a  = (const float*)d_in[1];
    const float* W1 = (const float*)d_in[2];
    const float* W2 = (const float*)d_in[3];
    const float* W3 = (const float*)d_in[4];
    const float* W4 = (const float*)d_in[5];
    const float* s1 = (const float*)d_in[6];
    const float* s2 = (const float*)d_in[7];
    float* out = (float*)d_out;
    (void)in_sizes; (void)n_in; (void)out_size; (void)ws_size;

    char* wp = (char*)d_ws;
    CARVE(int*,   ellA,  (size_t)NNODES * STRA * sizeof(int));   // 10.5 MB
    CARVE(int*,   cntA,  NNODES * sizeof(int));
    CARVE(int*,   diagA, NNODES * sizeof(int));
    CARVE(float*, dnA,   NNODES * sizeof(float));
    CARVE(float*, Z1,    (size_t)NNODES * FH * sizeof(float));
    CARVE(float*, X1,    (size_t)NNODES * FH * sizeof(float));
    CARVE(float*, sc1,   NNODES * sizeof(float));
    CARVE(int*,   rank1, NNODES * sizeof(int));
    CARVE(int*,   idx1,  NNODES * sizeof(int));
    CARVE(int*,   ellS,  (size_t)KP1 * STRS * sizeof(int));      // 5.2 MB
    CARVE(int*,   cntS,  KP1 * sizeof(int));
    CARVE(int*,   diagS, KP1 * sizeof(int));
    CARVE(float*, dnS,   KP1 * sizeof(float));
    CARVE(float*, Z2f,   (size_t)NNODES * FH * sizeof(float));   // X1@W2 over ALL rows
    CARVE(float*, X2,    (size_t)KP1 * FH * sizeof(float));
    CARVE(float*, sc2,   KP1 * sizeof(float));
    CARVE(int*,   rank2, KP1 * sizeof(int));
    CARVE(int*,   idx2,  KP1 * sizeof(int));
    CARVE(float*, Z3f,   (size_t)KP1 * FH * sizeof(float));      // X2@W3 over all pooled rows
    CARVE(float*, Z4r,   (size_t)KP1 * COUT * sizeof(float));    // rank-space X3@W4

    // 1) one full 256MB pass -> ELL (block-local counting) + co-launched Z1 = x@W1
    build_ell<<<NNODES + (NNODES * FH) / 256, 256, 0, stream>>>(
        a, NNODES, STRA, ellA, cntA, diagA, dnA, x, W1, Z1, FIN);
    // 2) GCN1: X1 = relu(Anorm@Z1), sc1 = X1@s1
    spmm_f32<<<NNODES / 4, 256, 0, stream>>>(ellA, cntA, diagA, dnA, Z1,
        (const int*)0, (const int*)0, X1, sc1, s1, (const float*)0, (float*)0, NNODES, STRA);
    // 3) pool1 top-k (block 0) + Z2f = X1@W2 over ALL rows (blocks 1..)
    topk_feat<<<1 + (NNODES * FH) / 256, 256, 0, stream>>>(
        sc1, NNODES, KP1, rank1, idx1, X1, W2, Z2f, FH);
    // 4) subgraph ELL
    build_subell<<<KP1 / 4, 256, 0, stream>>>(ellA, cntA, diagA, idx1, rank1,
        ellS, cntS, diagS, dnS, KP1, STRA, STRS);
    // 5) GCN2 on subgraph (Z gathered from full space via idx1): X2, sc2
    spmm_f32<<<KP1 / 4, 256, 0, stream>>>(ellS, cntS, diagS, dnS, Z2f,
        idx1, (const int*)0, X2, sc2, s2, (const float*)0, (float*)0, KP1, STRS);
    // 6) pool2 top-k (block 0) + Z3f = X2@W3 over all pooled rows (blocks 1..)
    topk_feat<<<1 + (KP1 * FH) / 256, 256, 0, stream>>>(
        sc2, KP1, KP2, rank2, idx2, X2, W3, Z3f, FH);
    // 7) GCN3 with pool2 mask + fused W4 epilogue -> Z4r = relu(Anorm_S@Z3_masked)@W4
    spmm_f32<<<KP1 / 4, 256, 0, stream>>>(ellS, cntS, diagS, dnS, Z3f,
        (const int*)0, rank2, (float*)0, (float*)0, (const float*)0, W4, Z4r, KP1, STRS);
    // 8) GCN4 + softmax (unpool1 folded into rank1 gather)
    spmm_out<<<NNODES / 4, 256, 0, stream>>>(ellA, cntA, diagA, dnA, Z4r, rank1, out, NNODES, STRA);
}

// Round 7
// 471.423 us; speedup vs baseline: 1.1102x; 1.0130x over previous
//
#include <hip/hip_runtime.h>
#include <stdint.h>

#define NNODES 8192
#define KP1 4096
#define KP2 2048
#define FIN 16
#define FH 32
#define COUT 2
#define STRA 320   // max off-diag nnz/row; mean ~163, sigma ~12.6 -> >12 sigma headroom
#define STRS 320

// Pass 1 (fused): blocks [0,n) stream the 256MB dense adjacency ONCE (float4, coalesced,
// block-local LDS counting) -> ELL; blocks [n,...) compute Zf = Xf @ Wf (fout=32).
__global__ __launch_bounds__(256) void build_ell(const float* __restrict__ A, int n, int stride,
        int* __restrict__ ell, int* __restrict__ rowcnt, int* __restrict__ diag, float* __restrict__ dnorm,
        const float* __restrict__ Xf, const float* __restrict__ Wf, float* __restrict__ Zf, int kf)
{
    if ((int)blockIdx.x >= n) {
        int t = ((int)blockIdx.x - n) * 256 + threadIdx.x;
        int i = t >> 5;
        int f = t & 31;
        const float* xr = Xf + (size_t)i * kf;
        float acc = 0.0f;
        for (int k = 0; k < kf; ++k) acc += xr[k] * Wf[k * 32 + f];
        Zf[t] = acc;
        return;
    }
    __shared__ int cnt;
    __shared__ int dg;
    int row = blockIdx.x;
    if (threadIdx.x == 0) { cnt = 0; dg = 0; }
    __syncthreads();
    const float4* arow4 = (const float4*)(A + (size_t)row * n);
    int* erow = ell + (size_t)row * stride;
    int n4 = n >> 2;
    for (int c4 = threadIdx.x; c4 < n4; c4 += 256) {
        float4 v = arow4[c4];
        // fast path: ~96% of quads are all-zero
        if (v.x == 0.0f && v.y == 0.0f && v.z == 0.0f && v.w == 0.0f) continue;
        int cb = c4 << 2;
        if (v.x != 0.0f) {
            if (cb == row) dg = 1;
            else { int p = atomicAdd(&cnt, 1); if (p < stride) erow[p] = cb; }
        }
        if (v.y != 0.0f) {
            int c = cb + 1;
            if (c == row) dg = 1;
            else { int p = atomicAdd(&cnt, 1); if (p < stride) erow[p] = c; }
        }
        if (v.z != 0.0f) {
            int c = cb + 2;
            if (c == row) dg = 1;
            else { int p = atomicAdd(&cnt, 1); if (p < stride) erow[p] = c; }
        }
        if (v.w != 0.0f) {
            int c = cb + 3;
            if (c == row) dg = 1;
            else { int p = atomicAdd(&cnt, 1); if (p < stride) erow[p] = c; }
        }
    }
    __syncthreads();
    if (threadIdx.x == 0) {
        int cf = cnt;
        rowcnt[row] = cf < stride ? cf : stride;
        diag[row] = dg;
        // deg_hat = offdiag_count + a_ii + 1 (self loop); all values are exactly 1.0
        dnorm[row] = rsqrtf((float)(cf + dg + 1) + 1e-10f);
    }
}

// SpMM (F=32) + relu. One wave per row; 8 lanes per neighbor, float4 per lane.
// remap: neighbor id c -> row of Z. maskp: skip c if maskp[c]<0.
// If z4out != 0: instead of storing X/scores, fuse epilogue Z4r[row] = relu_row @ W4p (32x2).
__global__ __launch_bounds__(256) void spmm_f32(const int* __restrict__ ell, const int* __restrict__ rowcnt,
        const int* __restrict__ diag, const float* __restrict__ dnorm, const float* __restrict__ Z,
        const int* __restrict__ remap, const int* __restrict__ maskp,
        float* __restrict__ X, float* __restrict__ scores, const float* __restrict__ svec,
        const float* __restrict__ W4p, float* __restrict__ z4out,
        int n, int stride)
{
    int wid = (blockIdx.x * 256 + threadIdx.x) >> 6;
    int lane = threadIdx.x & 63;
    if (wid >= n) return;
    int g = lane >> 3;   // neighbor sub-slot 0..7
    int q = lane & 7;    // feature quad 0..7
    int cnt = rowcnt[wid];
    const int* erow = ell + (size_t)wid * stride;
    float ax = 0.0f, ay = 0.0f, az = 0.0f, aw = 0.0f;
    for (int it = g; it < cnt; it += 8) {
        int c = erow[it];
        if (maskp && maskp[c] < 0) continue;
        int zc = c;
        if (remap) zc = remap[c];
        float dn = dnorm[c];
        const float4* zp = (const float4*)(Z + (size_t)zc * 32);
        float4 zv = zp[q];
        ax += dn * zv.x;
        ay += dn * zv.y;
        az += dn * zv.z;
        aw += dn * zv.w;
    }
    ax += __shfl_xor(ax, 8);
    ay += __shfl_xor(ay, 8);
    az += __shfl_xor(az, 8);
    aw += __shfl_xor(aw, 8);
    ax += __shfl_xor(ax, 16);
    ay += __shfl_xor(ay, 16);
    az += __shfl_xor(az, 16);
    aw += __shfl_xor(aw, 16);
    ax += __shfl_xor(ax, 32);
    ay += __shfl_xor(ay, 32);
    az += __shfl_xor(az, 32);
    aw += __shfl_xor(aw, 32);
    if (g == 0) {   // lanes 0..7 hold the full sum for feature quad q
        float dr = dnorm[wid];
        int selfok = 1;
        if (maskp && maskp[wid] < 0) selfok = 0;
        if (selfok) {
            int zc = wid;
            if (remap) zc = remap[wid];
            const float4* zp = (const float4*)(Z + (size_t)zc * 32);
            float4 zv = zp[q];
            float cf = (float)(diag[wid] + 1) * dr;
            ax += cf * zv.x;
            ay += cf * zv.y;
            az += cf * zv.z;
            aw += cf * zv.w;
        }
        float ox = fmaxf(dr * ax, 0.0f);
        float oy = fmaxf(dr * ay, 0.0f);
        float oz = fmaxf(dr * az, 0.0f);
        float ow = fmaxf(dr * aw, 0.0f);
        if (z4out) {
            // fused (32x2) GEMM: row @ W4 -> 2 outputs; reduce partials over the 8 q-lanes
            int kb = q * 4;
            float p0 = ox * W4p[(kb + 0) * 2 + 0] + oy * W4p[(kb + 1) * 2 + 0]
                     + oz * W4p[(kb + 2) * 2 + 0] + ow * W4p[(kb + 3) * 2 + 0];
            float p1 = ox * W4p[(kb + 0) * 2 + 1] + oy * W4p[(kb + 1) * 2 + 1]
                     + oz * W4p[(kb + 2) * 2 + 1] + ow * W4p[(kb + 3) * 2 + 1];
            p0 += __shfl_xor(p0, 1);
            p1 += __shfl_xor(p1, 1);
            p0 += __shfl_xor(p0, 2);
            p1 += __shfl_xor(p1, 2);
            p0 += __shfl_xor(p0, 4);
            p1 += __shfl_xor(p1, 4);
            if (q == 0) {
                float2 r;
                r.x = p0;
                r.y = p1;
                ((float2*)z4out)[wid] = r;
            }
        } else {
            float4 o;
            o.x = ox; o.y = oy; o.z = oz; o.w = ow;
            float4* xp = (float4*)(X + (size_t)wid * 32);
            xp[q] = o;
            if (scores) {
                const float4* sp = (const float4*)svec;
                float4 sv = sp[q];
                float p = o.x * sv.x + o.y * sv.y + o.z * sv.z + o.w * sv.w;
                p += __shfl_xor(p, 1);
                p += __shfl_xor(p, 2);
                p += __shfl_xor(p, 4);
                if (q == 0) scores[wid] = p;
            }
        }
    }
}

// Final SpMM (F=2) + 2-way softmax. Zr is rank-space (K1 x 2); node c contributes
// Zr[gat[c]] if gat[c]>=0 else 0 (unpool1 folded into the gather).
__global__ __launch_bounds__(256) void spmm_out(const int* __restrict__ ell, const int* __restrict__ rowcnt,
        const int* __restrict__ diag, const float* __restrict__ dnorm, const float* __restrict__ Zr,
        const int* __restrict__ gat, float* __restrict__ out, int n, int stride)
{
    int wid = (blockIdx.x * 256 + threadIdx.x) >> 6;
    int lane = threadIdx.x & 63;
    if (wid >= n) return;
    int cnt = rowcnt[wid];
    const int* erow = ell + (size_t)wid * stride;
    const float2* Z2 = (const float2*)Zr;
    float ax = 0.0f, ay = 0.0f;
    for (int it = lane; it < cnt; it += 64) {
        int c = erow[it];
        int rk = gat[c];
        if (rk >= 0) {
            float dn = dnorm[c];
            float2 zv = Z2[rk];
            ax += dn * zv.x;
            ay += dn * zv.y;
        }
    }
    ax += __shfl_xor(ax, 1);
    ay += __shfl_xor(ay, 1);
    ax += __shfl_xor(ax, 2);
    ay += __shfl_xor(ay, 2);
    ax += __shfl_xor(ax, 4);
    ay += __shfl_xor(ay, 4);
    ax += __shfl_xor(ax, 8);
    ay += __shfl_xor(ay, 8);
    ax += __shfl_xor(ax, 16);
    ay += __shfl_xor(ay, 16);
    ax += __shfl_xor(ax, 32);
    ay += __shfl_xor(ay, 32);
    if (lane == 0) {
        float dr = dnorm[wid];
        int rks = gat[wid];
        if (rks >= 0) {
            float cf = (float)(diag[wid] + 1) * dr;
            float2 zs = Z2[rks];
            ax += cf * zs.x;
            ay += cf * zs.y;
        }
        float v0 = dr * ax;
        float v1 = dr * ay;
        float m = fmaxf(v0, v1);
        float e0 = __expf(v0 - m);
        float e1 = __expf(v1 - m);
        float inv = 1.0f / (e0 + e1);
        float2 r;
        r.x = e0 * inv;
        r.y = e1 * inv;
        ((float2*)out)[wid] = r;
    }
}

// Exact top-K (jax.lax.top_k set semantics: value desc, index-asc ties), block 0 only.
// Blocks >= 1 compute Zf = Xf @ Wf (fout=32) — independent co-launched work.
// Scans use wave-internal guarded-shfl prefix (no barriers) + one cross-wave LDS combine,
// cutting ~80 __syncthreads per call (Hillis-Steele) to ~16.
__global__ __launch_bounds__(256) void topk_feat(const float* __restrict__ scores, int n, int K,
        int* __restrict__ rank, int* __restrict__ idxlist,
        const float* __restrict__ Xf, const float* __restrict__ Wf, float* __restrict__ Zf, int kf)
{
    if (blockIdx.x != 0) {
        int t = ((int)blockIdx.x - 1) * 256 + threadIdx.x;
        int i = t >> 5;
        int f = t & 31;
        const float* xr = Xf + (size_t)i * kf;
        float acc = 0.0f;
        for (int k = 0; k < kf; ++k) acc += xr[k] * Wf[k * 32 + f];
        Zf[t] = acc;
        return;
    }
    __shared__ unsigned int km_s[8192];
    __shared__ unsigned int histp[4][256];
    __shared__ unsigned int wsum[4];
    __shared__ unsigned int sh_pref;
    __shared__ unsigned int sh_rem;
    int tid = threadIdx.x;
    int wv = tid >> 6;
    int lane = tid & 63;
    int per = n >> 8;       // 32 (N=8192) or 16 (N=4096)
    int base = tid * per;
    for (int e = 0; e < per; ++e) {
        int v = base + e;
        unsigned int u = __float_as_uint(scores[v]);
        unsigned int m;
        if (u & 0x80000000u) m = ~u; else m = u | 0x80000000u;  // monotone asc in float
        km_s[v] = ~m;                                           // asc in km == desc in score
    }
    if (tid == 0) { sh_pref = 0u; sh_rem = (unsigned int)K; }
    __syncthreads();
    for (int bp = 3; bp >= 0; --bp) {
        histp[0][tid] = 0u;
        histp[1][tid] = 0u;
        histp[2][tid] = 0u;
        histp[3][tid] = 0u;
        __syncthreads();                 // (A) hist zeroed; prev-iter sh_pref visible
        unsigned int maskhi = 0u;
        if (bp < 3) maskhi = 0xFFFFFFFFu << ((bp + 1) * 8);
        unsigned int pref = sh_pref;
        unsigned int rem = sh_rem;
        for (int e = 0; e < per; ++e) {
            unsigned int km = km_s[base + e];
            if ((km & maskhi) == pref) atomicAdd(&histp[wv][(km >> (bp * 8)) & 255u], 1u);
        }
        __syncthreads();                 // (B) atomics done
        // thread tid owns bin tid; wave-internal inclusive scan (guarded shfl), then cross-wave combine
        unsigned int tot = histp[0][tid] + histp[1][tid] + histp[2][tid] + histp[3][tid];
        unsigned int v = tot;
        unsigned int t2;
        t2 = __shfl(v, lane - 1);  if (lane >= 1)  v += t2;
        t2 = __shfl(v, lane - 2);  if (lane >= 2)  v += t2;
        t2 = __shfl(v, lane - 4);  if (lane >= 4)  v += t2;
        t2 = __shfl(v, lane - 8);  if (lane >= 8)  v += t2;
        t2 = __shfl(v, lane - 16); if (lane >= 16) v += t2;
        t2 = __shfl(v, lane - 32); if (lane >= 32) v += t2;
        if (lane == 63) wsum[wv] = v;
        __syncthreads();                 // (C) wave sums visible
        unsigned int add = 0u;
        if (wv > 0) add += wsum[0];
        if (wv > 1) add += wsum[1];
        if (wv > 2) add += wsum[2];
        unsigned int cum = v + add;
        if (tot != 0u && cum >= rem && cum - tot < rem) {  // unique boundary bin
            sh_pref = pref | ((unsigned int)tid << (bp * 8));
            sh_rem = rem - (cum - tot);
        }
    }
    __syncthreads();                     // final sh_pref/sh_rem visible
    unsigned int T = sh_pref;       // K-th smallest km
    unsigned int need_eq = sh_rem;  // how many km==T to take (lowest node index first)
    // packed counts: high16 = #(km<T), low16 = #(km==T)
    unsigned int run = 0u;
    for (int e = 0; e < per; ++e) {
        unsigned int km = km_s[base + e];
        if (km < T) run += 0x10000u;
        else if (km == T) run += 1u;
    }
    unsigned int v2 = run;
    unsigned int t3;
    t3 = __shfl(v2, lane - 1);  if (lane >= 1)  v2 += t3;
    t3 = __shfl(v2, lane - 2);  if (lane >= 2)  v2 += t3;
    t3 = __shfl(v2, lane - 4);  if (lane >= 4)  v2 += t3;
    t3 = __shfl(v2, lane - 8);  if (lane >= 8)  v2 += t3;
    t3 = __shfl(v2, lane - 16); if (lane >= 16) v2 += t3;
    t3 = __shfl(v2, lane - 32); if (lane >= 32) v2 += t3;
    if (lane == 63) wsum[wv] = v2;
    __syncthreads();
    unsigned int add2 = 0u;
    if (wv > 0) add2 += wsum[0];
    if (wv > 1) add2 += wsum[1];
    if (wv > 2) add2 += wsum[2];
    unsigned int cur = v2 + add2 - run;   // exclusive prefix for this thread's chunk
    for (int e = 0; e < per; ++e) {
        int v = base + e;
        unsigned int km = km_s[v];
        unsigned int ltb = cur >> 16;
        unsigned int eqb = cur & 0xFFFFu;
        unsigned int eqs = eqb < need_eq ? eqb : need_eq;  // selected equals before v
        int sel = 0;
        if (km < T) { sel = 1; cur += 0x10000u; }
        else if (km == T) { if (eqb < need_eq) sel = 1; cur += 1u; }
        if (sel) {
            int r = (int)(ltb + eqs);       // rank = #selected with index < v
            rank[v] = r;
            idxlist[r] = v;
        } else {
            rank[v] = -1;
        }
    }
}

// Build subgraph ELL for A1p = a[idx1][:,idx1] by filtering the main ELL
// through rank1 (wave-compaction via ballot). One wave per subgraph row.
__global__ __launch_bounds__(256) void build_subell(const int* __restrict__ ellA, const int* __restrict__ rowcntA,
        const int* __restrict__ diagA, const int* __restrict__ idx1, const int* __restrict__ rank1,
        int* __restrict__ ellS, int* __restrict__ rowcntS, int* __restrict__ diagS, float* __restrict__ dnormS,
        int k1, int strideA, int strideS)
{
    int wid = (blockIdx.x * 256 + threadIdx.x) >> 6;
    int lane = threadIdx.x & 63;
    if (wid >= k1) return;
    int r = idx1[wid];
    int cnt = rowcntA[r];
    const int* erow = ellA + (size_t)r * strideA;
    int* srow = ellS + (size_t)wid * strideS;
    int outn = 0;
    for (int t0 = 0; t0 < cnt; t0 += 64) {
        int it = t0 + lane;
        int rk = -1;
        if (it < cnt) rk = rank1[erow[it]];
        unsigned long long b = __ballot(rk >= 0);
        int ofs = __popcll(b & ((1ull << lane) - 1ull));
        if (rk >= 0) srow[outn + ofs] = rk;
        outn += __popcll(b);
    }
    if (lane == 0) {
        int dg = diagA[r];              // A1p diagonal entry = a[r][r]
        rowcntS[wid] = outn;
        diagS[wid] = dg;
        dnormS[wid] = rsqrtf((float)(outn + dg + 1) + 1e-10f);
    }
}

#define CARVE(type, name, bytes) \
    type name = (type)wp; wp += (((size_t)(bytes)) + 255) & ~((size_t)255);

extern "C" void kernel_launch(void* const* d_in, const int* in_sizes, int n_in,
                              void* d_out, int out_size, void* d_ws, size_t ws_size,
                              hipStream_t stream)
{
    const float* x  = (const float*)d_in[0];
    const float* a  = (const float*)d_in[1];
    const float* W1 = (const float*)d_in[2];
    const float* W2 = (const float*)d_in[3];
    const float* W3 = (const float*)d_in[4];
    const float* W4 = (const float*)d_in[5];
    const float* s1 = (const float*)d_in[6];
    const float* s2 = (const float*)d_in[7];
    float* out = (float*)d_out;
    (void)in_sizes; (void)n_in; (void)out_size; (void)ws_size;

    char* wp = (char*)d_ws;
    CARVE(int*,   ellA,  (size_t)NNODES * STRA * sizeof(int));   // 10.5 MB
    CARVE(int*,   cntA,  NNODES * sizeof(int));
    CARVE(int*,   diagA, NNODES * sizeof(int));
    CARVE(float*, dnA,   NNODES * sizeof(float));
    CARVE(float*, Z1,    (size_t)NNODES * FH * sizeof(float));
    CARVE(float*, X1,    (size_t)NNODES * FH * sizeof(float));
    CARVE(float*, sc1,   NNODES * sizeof(float));
    CARVE(int*,   rank1, NNODES * sizeof(int));
    CARVE(int*,   idx1,  NNODES * sizeof(int));
    CARVE(int*,   ellS,  (size_t)KP1 * STRS * sizeof(int));      // 5.2 MB
    CARVE(int*,   cntS,  KP1 * sizeof(int));
    CARVE(int*,   diagS, KP1 * sizeof(int));
    CARVE(float*, dnS,   KP1 * sizeof(float));
    CARVE(float*, Z2f,   (size_t)NNODES * FH * sizeof(float));   // X1@W2 over ALL rows
    CARVE(float*, X2,    (size_t)KP1 * FH * sizeof(float));
    CARVE(float*, sc2,   KP1 * sizeof(float));
    CARVE(int*,   rank2, KP1 * sizeof(int));
    CARVE(int*,   idx2,  KP1 * sizeof(int));
    CARVE(float*, Z3f,   (size_t)KP1 * FH * sizeof(float));      // X2@W3 over all pooled rows
    CARVE(float*, Z4r,   (size_t)KP1 * COUT * sizeof(float));    // rank-space X3@W4

    // 1) one full 256MB pass -> ELL (block-local counting) + co-launched Z1 = x@W1
    build_ell<<<NNODES + (NNODES * FH) / 256, 256, 0, stream>>>(
        a, NNODES, STRA, ellA, cntA, diagA, dnA, x, W1, Z1, FIN);
    // 2) GCN1: X1 = relu(Anorm@Z1), sc1 = X1@s1
    spmm_f32<<<NNODES / 4, 256, 0, stream>>>(ellA, cntA, diagA, dnA, Z1,
        (const int*)0, (const int*)0, X1, sc1, s1, (const float*)0, (float*)0, NNODES, STRA);
    // 3) pool1 top-k (block 0) + Z2f = X1@W2 over ALL rows (blocks 1..)
    topk_feat<<<1 + (NNODES * FH) / 256, 256, 0, stream>>>(
        sc1, NNODES, KP1, rank1, idx1, X1, W2, Z2f, FH);
    // 4) subgraph ELL
    build_subell<<<KP1 / 4, 256, 0, stream>>>(ellA, cntA, diagA, idx1, rank1,
        ellS, cntS, diagS, dnS, KP1, STRA, STRS);
    // 5) GCN2 on subgraph (Z gathered from full space via idx1): X2, sc2
    spmm_f32<<<KP1 / 4, 256, 0, stream>>>(ellS, cntS, diagS, dnS, Z2f,
        idx1, (const int*)0, X2, sc2, s2, (const float*)0, (float*)0, KP1, STRS);
    // 6) pool2 top-k (block 0) + Z3f = X2@W3 over all pooled rows (blocks 1..)
    topk_feat<<<1 + (KP1 * FH) / 256, 256, 0, stream>>>(
        sc2, KP1, KP2, rank2, idx2, X2, W3, Z3f, FH);
    // 7) GCN3 with pool2 mask + fused W4 epilogue -> Z4r = relu(Anorm_S@Z3_masked)@W4
    spmm_f32<<<KP1 / 4, 256, 0, stream>>>(ellS, cntS, diagS, dnS, Z3f,
        (const int*)0, rank2, (float*)0, (float*)0, (const float*)0, W4, Z4r, KP1, STRS);
    // 8) GCN4 + softmax (unpool1 folded into rank1 gather)
    spmm_out<<<NNODES / 4, 256, 0, stream>>>(ellA, cntA, diagA, dnA, Z4r, rank1, out, NNODES, STRA);
}